// Round 1
// baseline (727.852 us; speedup 1.0000x reference)
//
#include <hip/hip_runtime.h>
#include <math.h>

// Problem constants
#define BB 256
#define NE 400
#define NP (BB * NE)        // 102400 pairs
#define HID 256
#define NCOP 224
#define DIN 480
#define PPB 32              // pairs per block (fused kernel)
#define NBLK (NP / PPB)     // 3200

static __device__ __forceinline__ float silu_f(float x) {
    return x / (1.0f + __expf(-x));
}

// ---------------------------------------------------------------------------
// Precompute kernel:
//  E1[e][n]  = e_feat[e] @ mW1[0:32]                 (400 x 256)
//  F1[b][n]  = field[b] @ mW1[32:96] + mb1           (256 x 256)
//  Fo[b][n]  = field[b] @ oW1[224:288] + ob1         (256 x 256)
//  S[b][c]   = mean(x^2) per copy for l=1 (c<64, dim3) and l=2 (c in 64..95, dim5)
// ---------------------------------------------------------------------------
__global__ void precompute_kernel(const float* __restrict__ h_abs,
                                  const float* __restrict__ e_feat,
                                  const float* __restrict__ field,
                                  const float* __restrict__ mW1,
                                  const float* __restrict__ mb1,
                                  const float* __restrict__ oW1,
                                  const float* __restrict__ ob1,
                                  float* __restrict__ E1,
                                  float* __restrict__ F1,
                                  float* __restrict__ Fo,
                                  float* __restrict__ S)
{
    int r = blockIdx.x;
    int t = threadIdx.x;
    if (r < NE) {
        float a = 0.f;
        #pragma unroll
        for (int k = 0; k < 32; ++k) a += e_feat[r * 32 + k] * mW1[k * HID + t];
        E1[r * HID + t] = a;
    } else if (r < NE + BB) {
        int b = r - NE;
        float a = mb1[t];
        #pragma unroll
        for (int k = 0; k < 64; ++k) a += field[b * 64 + k] * mW1[(32 + k) * HID + t];
        F1[b * HID + t] = a;
    } else if (r < NE + 2 * BB) {
        int b = r - NE - BB;
        float a = ob1[t];
        #pragma unroll
        for (int k = 0; k < 64; ++k) a += field[b * 64 + k] * oW1[(224 + k) * HID + t];
        Fo[b * HID + t] = a;
    } else {
        int b = r - NE - 2 * BB;
        if (t < 64) {
            const float* x = h_abs + b * DIN + 128 + t * 3;
            S[b * 96 + t] = (x[0]*x[0] + x[1]*x[1] + x[2]*x[2]) * (1.0f / 3.0f);
        } else if (t < 96) {
            int c = t - 64;
            const float* x = h_abs + b * DIN + 320 + c * 5;
            float s = 0.f;
            #pragma unroll
            for (int d = 0; d < 5; ++d) s += x[d] * x[d];
            S[b * 96 + t] = s * 0.2f;
        }
    }
}

// GEMM phase helper: acc[pp][i] = sum_k sh[ty*8+pp][k] * W[k][tx+64*i]
// K multiple of 4. NOUT==256 (full) or 224 (guard 4th column group).
template <int K, int NOUT>
static __device__ __forceinline__ void gemm_phase(const float (*sh)[HID],
                                                  const float* __restrict__ W,
                                                  int tx, int ty,
                                                  float acc[8][4])
{
    #pragma unroll
    for (int pp = 0; pp < 8; ++pp)
        #pragma unroll
        for (int i = 0; i < 4; ++i) acc[pp][i] = 0.f;

    for (int k = 0; k < K; k += 4) {
        float4 hv[8];
        #pragma unroll
        for (int pp = 0; pp < 8; ++pp)
            hv[pp] = *reinterpret_cast<const float4*>(&sh[ty * 8 + pp][k]);
        #pragma unroll
        for (int kk = 0; kk < 4; ++kk) {
            const float* wrow = W + (size_t)(k + kk) * NOUT;
            float w0 = wrow[tx];
            float w1 = wrow[tx + 64];
            float w2 = wrow[tx + 128];
            float w3;
            if (NOUT == 256) w3 = wrow[tx + 192];
            else             w3 = (tx < 32) ? wrow[tx + 192] : 0.f;
            #pragma unroll
            for (int pp = 0; pp < 8; ++pp) {
                float h = reinterpret_cast<const float*>(&hv[pp])[kk];
                acc[pp][0] += h * w0;
                acc[pp][1] += h * w1;
                acc[pp][2] += h * w2;
                acc[pp][3] += h * w3;
            }
        }
    }
}

// ---------------------------------------------------------------------------
// Fused per-pair kernel: 32 pairs / block, 256 threads.
// ---------------------------------------------------------------------------
__global__ __launch_bounds__(256)
void fused_kernel(const float* __restrict__ h_abs,
                  const float* __restrict__ mW2, const float* __restrict__ mb2,
                  const float* __restrict__ mW3, const float* __restrict__ mb3,
                  const float* __restrict__ oW1,
                  const float* __restrict__ oW2, const float* __restrict__ ob2,
                  const float* __restrict__ oW3, const float* __restrict__ ob3,
                  const float* __restrict__ E1, const float* __restrict__ F1,
                  const float* __restrict__ Fo, const float* __restrict__ S,
                  float* __restrict__ out)
{
    __shared__ float sh[PPB][HID];     // 32 KB: activation buffer, reused per phase
    __shared__ float sred[256];        // final-dot reduction

    const int blk = blockIdx.x;
    const int p0  = blk * PPB;
    const int t   = threadIdx.x;
    const int tx  = t & 63;
    const int ty  = t >> 6;

    // ---- Phase A: h1 = silu(E1[e] + F1[b])  (F1 includes mb1) ----
    for (int i = 0; i < PPB; ++i) {
        int p = p0 + i;
        int b = p / NE;
        int e = p - b * NE;
        float v = E1[e * HID + t] + F1[b * HID + t];
        sh[i][t] = silu_f(v);
    }
    __syncthreads();

    float acc[8][4];

    // ---- Phase B: h2 = silu(h1 @ mW2 + mb2) ----
    gemm_phase<HID, HID>(sh, mW2, tx, ty, acc);
    __syncthreads();
    #pragma unroll
    for (int pp = 0; pp < 8; ++pp)
        #pragma unroll
        for (int i = 0; i < 4; ++i) {
            int n = tx + 64 * i;
            sh[ty * 8 + pp][n] = silu_f(acc[pp][i] + mb2[n]);
        }
    __syncthreads();

    // ---- Phase C: g = h2 @ mW3 + mb3; inv transform into sh ----
    gemm_phase<HID, NCOP>(sh, mW3, tx, ty, acc);
    __syncthreads();
    #pragma unroll
    for (int pp = 0; pp < 8; ++pp) {
        int p = p0 + ty * 8 + pp;
        int b = p / NE;
        #pragma unroll
        for (int i = 0; i < 4; ++i) {
            int n = tx + 64 * i;
            if (n < NCOP) {
                float g = acc[pp][i] + mb3[n];
                float invv;
                if (n < 128) {
                    invv = h_abs[b * DIN + n] * g;   // l=0 scalars pass through
                } else {
                    float s = S[b * 96 + (n - 128)];
                    invv = sqrtf(g * g * s + 1e-8f);
                }
                sh[ty * 8 + pp][n] = invv;
            }
        }
    }
    __syncthreads();

    // ---- Phase D: o1 = silu(inv @ oW1[0:224] + Fo[b])  (Fo includes ob1) ----
    gemm_phase<NCOP, HID>(sh, oW1, tx, ty, acc);
    __syncthreads();
    #pragma unroll
    for (int pp = 0; pp < 8; ++pp) {
        int p = p0 + ty * 8 + pp;
        int b = p / NE;
        #pragma unroll
        for (int i = 0; i < 4; ++i) {
            int n = tx + 64 * i;
            sh[ty * 8 + pp][n] = silu_f(acc[pp][i] + Fo[b * HID + n]);
        }
    }
    __syncthreads();

    // ---- Phase E: o2 = silu(o1 @ oW2 + ob2) ----
    gemm_phase<HID, HID>(sh, oW2, tx, ty, acc);
    __syncthreads();
    #pragma unroll
    for (int pp = 0; pp < 8; ++pp)
        #pragma unroll
        for (int i = 0; i < 4; ++i) {
            int n = tx + 64 * i;
            sh[ty * 8 + pp][n] = silu_f(acc[pp][i] + ob2[n]);
        }
    __syncthreads();

    // ---- Phase F: out[p] = o2[p] . oW3 + ob3 ----
    {
        int pF  = t >> 3;   // 0..31
        int seg = t & 7;    // 0..7
        float s = 0.f;
        int kbase = seg * 32;
        #pragma unroll
        for (int k = 0; k < 32; ++k) s += sh[pF][kbase + k] * oW3[kbase + k];
        sred[t] = s;
        __syncthreads();
        if (seg == 0) {
            float tot = ob3[0];
            #pragma unroll
            for (int j = 0; j < 8; ++j) tot += sred[t + j];
            out[p0 + pF] = tot;
        }
    }
}

extern "C" void kernel_launch(void* const* d_in, const int* in_sizes, int n_in,
                              void* d_out, int out_size, void* d_ws, size_t ws_size,
                              hipStream_t stream) {
    const float* h_abs  = (const float*)d_in[0];
    const float* e_feat = (const float*)d_in[1];
    const float* field  = (const float*)d_in[2];
    const float* mW1 = (const float*)d_in[3];
    const float* mb1 = (const float*)d_in[4];
    const float* mW2 = (const float*)d_in[5];
    const float* mb2 = (const float*)d_in[6];
    const float* mW3 = (const float*)d_in[7];
    const float* mb3 = (const float*)d_in[8];
    const float* oW1 = (const float*)d_in[9];
    const float* ob1 = (const float*)d_in[10];
    const float* oW2 = (const float*)d_in[11];
    const float* ob2 = (const float*)d_in[12];
    const float* oW3 = (const float*)d_in[13];
    const float* ob3 = (const float*)d_in[14];
    float* out = (float*)d_out;

    // Workspace layout (floats)
    float* ws = (float*)d_ws;
    float* E1 = ws;                      // 400*256 = 102400
    float* F1 = E1 + NE * HID;           // 256*256 =  65536
    float* Fo = F1 + BB * HID;           // 256*256 =  65536
    float* S  = Fo + BB * HID;           // 256*96  =  24576

    precompute_kernel<<<NE + 3 * BB, 256, 0, stream>>>(
        h_abs, e_feat, field, mW1, mb1, oW1, ob1, E1, F1, Fo, S);

    fused_kernel<<<NBLK, 256, 0, stream>>>(
        h_abs, mW2, mb2, mW3, mb3, oW1, oW2, ob2, oW3, ob3,
        E1, F1, Fo, S, out);
}

// Round 2
// 491.478 us; speedup vs baseline: 1.4809x; 1.4809x over previous
//
#include <hip/hip_runtime.h>
#include <math.h>

// Problem constants
#define BB 256
#define NE 400
#define NP (BB * NE)        // 102400 pairs
#define HID 256
#define NCOP 224
#define DIN 480
#define MBLK 128            // pairs per block in fused MFMA kernel
#define NBLK (NP / MBLK)    // 800

typedef _Float16 half8 __attribute__((ext_vector_type(8)));
typedef float f4 __attribute__((ext_vector_type(4)));

static __device__ __forceinline__ float silu_f(float x) {
    return x / (1.0f + __expf(-x));
}

// Swizzled byte offset into the activation LDS buffer.
// Row stride = 512 B (256 f16). XOR row&7 into bits 4..6 -> ds_read_b128
// A-fragment reads are bank-balanced (8 lanes per 16B group).
static __device__ __forceinline__ int swz(int row, int colbyte) {
    return (row * 512 + colbyte) ^ ((row & 7) << 4);
}

// ---------------------------------------------------------------------------
// Precompute (fp32):
//  E1[e][n]  = e_feat[e] @ mW1[0:32]                 (400 x 256)
//  F1[b][n]  = field[b] @ mW1[32:96] + mb1           (256 x 256)
//  Fo[b][n]  = field[b] @ oW1[224:288] + ob1         (256 x 256)
//  S[b][c]   = mean(x^2) per copy: l=1 (c<64, dim3), l=2 (c 64..95, dim5)
// ---------------------------------------------------------------------------
__global__ void precompute_kernel(const float* __restrict__ h_abs,
                                  const float* __restrict__ e_feat,
                                  const float* __restrict__ field,
                                  const float* __restrict__ mW1,
                                  const float* __restrict__ mb1,
                                  const float* __restrict__ oW1,
                                  const float* __restrict__ ob1,
                                  float* __restrict__ E1,
                                  float* __restrict__ F1,
                                  float* __restrict__ Fo,
                                  float* __restrict__ S)
{
    int r = blockIdx.x;
    int t = threadIdx.x;
    if (r < NE) {
        float a = 0.f;
        #pragma unroll
        for (int k = 0; k < 32; ++k) a += e_feat[r * 32 + k] * mW1[k * HID + t];
        E1[r * HID + t] = a;
    } else if (r < NE + BB) {
        int b = r - NE;
        float a = mb1[t];
        #pragma unroll
        for (int k = 0; k < 64; ++k) a += field[b * 64 + k] * mW1[(32 + k) * HID + t];
        F1[b * HID + t] = a;
    } else if (r < NE + 2 * BB) {
        int b = r - NE - BB;
        float a = ob1[t];
        #pragma unroll
        for (int k = 0; k < 64; ++k) a += field[b * 64 + k] * oW1[(224 + k) * HID + t];
        Fo[b * HID + t] = a;
    } else {
        int b = r - NE - 2 * BB;
        if (t < 64) {
            const float* x = h_abs + b * DIN + 128 + t * 3;
            S[b * 96 + t] = (x[0]*x[0] + x[1]*x[1] + x[2]*x[2]) * (1.0f / 3.0f);
        } else if (t < 96) {
            int c = t - 64;
            const float* x = h_abs + b * DIN + 320 + c * 5;
            float s = 0.f;
            #pragma unroll
            for (int d = 0; d < 5; ++d) s += x[d] * x[d];
            S[b * 96 + t] = s * 0.2f;
        }
    }
}

// ---------------------------------------------------------------------------
// Pack weights (fp32 -> fp16) into MFMA B-fragment order.
// Frag (nt, ks), lane l, elem j holds W[ks*32 + (l>>4)*8 + j][nt*16 + (l&15)].
// Stored contiguously: P[((nt*KST + ks)*64 + l)*8 + j] -> one half8 per lane.
// Grid: 128 (mW2) + 112 (mW3) + 112 (oW1 rows 0..223) + 128 (oW2) = 480 blocks x 64.
// ---------------------------------------------------------------------------
__global__ void pack_weights(const float* __restrict__ mW2, const float* __restrict__ mW3,
                             const float* __restrict__ oW1, const float* __restrict__ oW2,
                             _Float16* __restrict__ PB2, _Float16* __restrict__ PB3,
                             _Float16* __restrict__ PO1, _Float16* __restrict__ PO2)
{
    int blk = blockIdx.x;
    int l = threadIdx.x;
    const float* W; _Float16* P; int LD;
    if (blk < 128)      { W = mW2; P = PB2; LD = 256; }
    else if (blk < 240) { blk -= 128; W = mW3; P = PB3; LD = 224; }
    else if (blk < 352) { blk -= 240; W = oW1; P = PO1; LD = 256; }
    else                { blk -= 352; W = oW2; P = PO2; LD = 256; }
    // blk == nt*KST + ks; the k0/n decomposition below only needs KST via blk
    // for PB3/PO1 the caller-side layout uses the same linear blk indexing.
    int KST = (P == PO1) ? 7 : 8;
    int nt = blk / KST, ks = blk - nt * KST;
    int n  = nt * 16 + (l & 15);
    int k0 = ks * 32 + (l >> 4) * 8;
    half8 v;
    #pragma unroll
    for (int j = 0; j < 8; ++j) v[j] = (_Float16)W[(size_t)(k0 + j) * LD + n];
    *(half8*)&P[(size_t)(blk * 64 + l) * 8] = v;
}

// ---------------------------------------------------------------------------
// One GEMM phase on the matrix pipe.
// Wave computes 8 m-tiles x NTW n-tiles, K = KST*32.
// A from swizzled LDS (ds_read_b128), B from packed global frags (L2).
// ---------------------------------------------------------------------------
template<int NTW, int KST>
static __device__ __forceinline__ void mma_phase(const half8* __restrict__ Wp,
                                                 const char* actp, int lane,
                                                 f4 acc[8][4])
{
    #pragma unroll
    for (int mt = 0; mt < 8; ++mt)
        #pragma unroll
        for (int nt = 0; nt < NTW; ++nt)
            acc[mt][nt] = (f4){0.f, 0.f, 0.f, 0.f};

    for (int ks = 0; ks < KST; ++ks) {
        int kb = ks * 64 + ((lane >> 4) << 4);   // (ks*32 + (lane>>4)*8) * 2 bytes
        half8 a[8];
        #pragma unroll
        for (int mt = 0; mt < 8; ++mt) {
            int row = mt * 16 + (lane & 15);
            a[mt] = *(const half8*)(actp + ((row * 512 + kb) ^ ((row & 7) << 4)));
        }
        #pragma unroll
        for (int nt = 0; nt < NTW; ++nt) {
            half8 b = Wp[(nt * KST + ks) * 64 + lane];
            #pragma unroll
            for (int mt = 0; mt < 8; ++mt)
                acc[mt][nt] = __builtin_amdgcn_mfma_f32_16x16x32_f16(a[mt], b, acc[mt][nt], 0, 0, 0);
        }
    }
}

// ---------------------------------------------------------------------------
// Fused kernel: 128 pairs / block, 256 threads (4 waves).
// Wave w owns output columns [w*64, w*64+64).
// ---------------------------------------------------------------------------
__global__ __launch_bounds__(256, 2)
void fused_mfma(const float* __restrict__ h_abs,
                const float* __restrict__ mb2, const float* __restrict__ mb3,
                const float* __restrict__ ob2,
                const float* __restrict__ oW3, const float* __restrict__ ob3,
                const float* __restrict__ E1, const float* __restrict__ F1,
                const float* __restrict__ Fo, const float* __restrict__ S,
                const half8* __restrict__ PB2, const half8* __restrict__ PB3,
                const half8* __restrict__ PO1, const half8* __restrict__ PO2,
                float* __restrict__ out)
{
    __shared__ char act[MBLK * 512];   // 64 KB f16 activations [128][256]

    const int t    = threadIdx.x;
    const int lane = t & 63;
    const int w    = t >> 6;
    const int p0   = blockIdx.x * MBLK;
    const int lr   = lane & 15;
    const int lq   = lane >> 4;

    // ---- Phase A: h1 = silu(E1[e] + F1[b])  -> act (f16) ----
    {
        int c0   = (t & 31) * 8;
        int rsub = t >> 5;
        for (int i = 0; i < 16; ++i) {
            int row = i * 8 + rsub;
            int p = p0 + row;
            int b = p / NE;
            int e = p - b * NE;
            const float4* ep = (const float4*)&E1[e * HID + c0];
            const float4* fp = (const float4*)&F1[b * HID + c0];
            float4 e0 = ep[0], e1 = ep[1];
            float4 f0 = fp[0], f1 = fp[1];
            half8 hv;
            hv[0] = (_Float16)silu_f(e0.x + f0.x);
            hv[1] = (_Float16)silu_f(e0.y + f0.y);
            hv[2] = (_Float16)silu_f(e0.z + f0.z);
            hv[3] = (_Float16)silu_f(e0.w + f0.w);
            hv[4] = (_Float16)silu_f(e1.x + f1.x);
            hv[5] = (_Float16)silu_f(e1.y + f1.y);
            hv[6] = (_Float16)silu_f(e1.z + f1.z);
            hv[7] = (_Float16)silu_f(e1.w + f1.w);
            *(half8*)(act + swz(row, c0 * 2)) = hv;
        }
    }
    __syncthreads();

    f4 acc[8][4];

    // ---- Phase B: h2 = silu(h1 @ mW2 + mb2) ----
    mma_phase<4, 8>(PB2 + (w * 4) * 8 * 64, act, lane, acc);
    __syncthreads();
    #pragma unroll
    for (int nt = 0; nt < 4; ++nt) {
        int n = w * 64 + nt * 16 + lr;
        float bias = mb2[n];
        #pragma unroll
        for (int mt = 0; mt < 8; ++mt)
            #pragma unroll
            for (int r = 0; r < 4; ++r) {
                int row = mt * 16 + lq * 4 + r;
                *(_Float16*)(act + swz(row, n * 2)) =
                    (_Float16)silu_f(acc[mt][nt][r] + bias);
            }
    }
    __syncthreads();

    // ---- Phase C: g = h2 @ mW3 + mb3 ; fused invariant transform ----
    if (w < 3) mma_phase<4, 8>(PB3 + (w * 4) * 8 * 64, act, lane, acc);
    else       mma_phase<2, 8>(PB3 + 12 * 8 * 64,      act, lane, acc);
    __syncthreads();
    #pragma unroll
    for (int nt = 0; nt < 4; ++nt) {
        int n = w * 64 + nt * 16 + lr;
        if (n < NCOP) {
            float bias = mb3[n];
            #pragma unroll
            for (int mt = 0; mt < 8; ++mt)
                #pragma unroll
                for (int r = 0; r < 4; ++r) {
                    int row = mt * 16 + lq * 4 + r;
                    int p = p0 + row;
                    int b = p / NE;
                    float g = acc[mt][nt][r] + bias;
                    float invv;
                    if (n < 128) invv = h_abs[b * DIN + n] * g;       // l=0 scalars
                    else         invv = sqrtf(g * g * S[b * 96 + (n - 128)] + 1e-8f);
                    *(_Float16*)(act + swz(row, n * 2)) = (_Float16)invv;
                }
        }
    }
    __syncthreads();

    // ---- Phase D: o1 = silu(inv @ oW1[0:224] + Fo[b])  (Fo includes ob1) ----
    mma_phase<4, 7>(PO1 + (w * 4) * 7 * 64, act, lane, acc);
    __syncthreads();
    #pragma unroll
    for (int nt = 0; nt < 4; ++nt) {
        int n = w * 64 + nt * 16 + lr;
        #pragma unroll
        for (int mt = 0; mt < 8; ++mt)
            #pragma unroll
            for (int r = 0; r < 4; ++r) {
                int row = mt * 16 + lq * 4 + r;
                int p = p0 + row;
                int b = p / NE;
                *(_Float16*)(act + swz(row, n * 2)) =
                    (_Float16)silu_f(acc[mt][nt][r] + Fo[b * HID + n]);
            }
    }
    __syncthreads();

    // ---- Phase E: o2 = silu(o1 @ oW2 + ob2) ----
    mma_phase<4, 8>(PO2 + (w * 4) * 8 * 64, act, lane, acc);
    __syncthreads();
    #pragma unroll
    for (int nt = 0; nt < 4; ++nt) {
        int n = w * 64 + nt * 16 + lr;
        float bias = ob2[n];
        #pragma unroll
        for (int mt = 0; mt < 8; ++mt)
            #pragma unroll
            for (int r = 0; r < 4; ++r) {
                int row = mt * 16 + lq * 4 + r;
                *(_Float16*)(act + swz(row, n * 2)) =
                    (_Float16)silu_f(acc[mt][nt][r] + bias);
            }
    }
    __syncthreads();

    // ---- Phase F: out[p] = o2[p] . oW3 + ob3  (fp32 dot, 2 threads/pair) ----
    {
        int pF = t >> 1;
        int hf = t & 1;
        float s = 0.f;
        #pragma unroll
        for (int q = 0; q < 16; ++q) {
            half8 v = *(const half8*)(act + swz(pF, hf * 256 + q * 16));
            const float4* wp = (const float4*)&oW3[hf * 128 + q * 8];
            float4 wa = wp[0], wb = wp[1];
            s += (float)v[0] * wa.x + (float)v[1] * wa.y +
                 (float)v[2] * wa.z + (float)v[3] * wa.w +
                 (float)v[4] * wb.x + (float)v[5] * wb.y +
                 (float)v[6] * wb.z + (float)v[7] * wb.w;
        }
        s += __shfl_xor(s, 1, 64);
        if (hf == 0) out[p0 + pF] = s + ob3[0];
    }
}

extern "C" void kernel_launch(void* const* d_in, const int* in_sizes, int n_in,
                              void* d_out, int out_size, void* d_ws, size_t ws_size,
                              hipStream_t stream) {
    const float* h_abs  = (const float*)d_in[0];
    const float* e_feat = (const float*)d_in[1];
    const float* field  = (const float*)d_in[2];
    const float* mW1 = (const float*)d_in[3];
    const float* mb1 = (const float*)d_in[4];
    const float* mW2 = (const float*)d_in[5];
    const float* mb2 = (const float*)d_in[6];
    const float* mW3 = (const float*)d_in[7];
    const float* mb3 = (const float*)d_in[8];
    const float* oW1 = (const float*)d_in[9];
    const float* ob1 = (const float*)d_in[10];
    const float* oW2 = (const float*)d_in[11];
    const float* ob2 = (const float*)d_in[12];
    const float* oW3 = (const float*)d_in[13];
    const float* ob3 = (const float*)d_in[14];
    float* out = (float*)d_out;

    // Workspace layout
    float* ws = (float*)d_ws;
    float* E1 = ws;                      // 400*256 = 102400 f
    float* F1 = E1 + NE * HID;           // 65536 f
    float* Fo = F1 + BB * HID;           // 65536 f
    float* S  = Fo + BB * HID;           // 24576 f
    _Float16* PB2 = (_Float16*)(S + BB * 96);   // 16*8*64*8 = 65536 h
    _Float16* PB3 = PB2 + 16 * 8 * 64 * 8;      // 14*8*64*8 = 57344 h
    _Float16* PO1 = PB3 + 14 * 8 * 64 * 8;      // 16*7*64*8 = 57344 h
    _Float16* PO2 = PO1 + 16 * 7 * 64 * 8;      // 16*8*64*8 = 65536 h

    precompute_kernel<<<NE + 3 * BB, 256, 0, stream>>>(
        h_abs, e_feat, field, mW1, mb1, oW1, ob1, E1, F1, Fo, S);

    pack_weights<<<480, 64, 0, stream>>>(
        mW2, mW3, oW1, oW2, PB2, PB3, PO1, PO2);

    fused_mfma<<<NBLK, 256, 0, stream>>>(
        h_abs, mb2, mb3, ob2, oW3, ob3,
        E1, F1, Fo, S,
        (const half8*)PB2, (const half8*)PB3, (const half8*)PO1, (const half8*)PO2,
        out);
}

// Round 3
// 178.404 us; speedup vs baseline: 4.0798x; 2.7549x over previous
//
#include <hip/hip_runtime.h>
#include <math.h>

// Problem constants
#define BB 256
#define NE 400
#define NP (BB * NE)        // 102400 pairs
#define HID 256
#define NCOP 224
#define DIN 480
#define MBLK 64             // pairs per block in fused MFMA kernel
#define NBLK (NP / MBLK)    // 1600

typedef _Float16 half8 __attribute__((ext_vector_type(8)));
typedef float f4 __attribute__((ext_vector_type(4)));

static __device__ __forceinline__ float silu_f(float x) {
    return x / (1.0f + __expf(-x));
}

// Swizzled byte offset into the activation LDS buffer.
// Row stride = 512 B (256 f16). XOR row&7 into bits 4..6 -> ds_read_b128
// A-fragment reads are bank-balanced.
static __device__ __forceinline__ int swz(int row, int colbyte) {
    return (row * 512 + colbyte) ^ ((row & 7) << 4);
}

// ---------------------------------------------------------------------------
// Precompute (fp32):
//  E1[e][n]  = e_feat[e] @ mW1[0:32]                 (400 x 256)
//  F1[b][n]  = field[b] @ mW1[32:96] + mb1           (256 x 256)
//  Fo[b][n]  = field[b] @ oW1[224:288] + ob1         (256 x 256)
//  S[b][c]   = mean(x^2) per copy: l=1 (c<64, dim3), l=2 (c 64..95, dim5)
// ---------------------------------------------------------------------------
__global__ void precompute_kernel(const float* __restrict__ h_abs,
                                  const float* __restrict__ e_feat,
                                  const float* __restrict__ field,
                                  const float* __restrict__ mW1,
                                  const float* __restrict__ mb1,
                                  const float* __restrict__ oW1,
                                  const float* __restrict__ ob1,
                                  float* __restrict__ E1,
                                  float* __restrict__ F1,
                                  float* __restrict__ Fo,
                                  float* __restrict__ S)
{
    int r = blockIdx.x;
    int t = threadIdx.x;
    if (r < NE) {
        float a = 0.f;
        #pragma unroll
        for (int k = 0; k < 32; ++k) a += e_feat[r * 32 + k] * mW1[k * HID + t];
        E1[r * HID + t] = a;
    } else if (r < NE + BB) {
        int b = r - NE;
        float a = mb1[t];
        #pragma unroll
        for (int k = 0; k < 64; ++k) a += field[b * 64 + k] * mW1[(32 + k) * HID + t];
        F1[b * HID + t] = a;
    } else if (r < NE + 2 * BB) {
        int b = r - NE - BB;
        float a = ob1[t];
        #pragma unroll
        for (int k = 0; k < 64; ++k) a += field[b * 64 + k] * oW1[(224 + k) * HID + t];
        Fo[b * HID + t] = a;
    } else {
        int b = r - NE - 2 * BB;
        if (t < 64) {
            const float* x = h_abs + b * DIN + 128 + t * 3;
            S[b * 96 + t] = (x[0]*x[0] + x[1]*x[1] + x[2]*x[2]) * (1.0f / 3.0f);
        } else if (t < 96) {
            int c = t - 64;
            const float* x = h_abs + b * DIN + 320 + c * 5;
            float s = 0.f;
            #pragma unroll
            for (int d = 0; d < 5; ++d) s += x[d] * x[d];
            S[b * 96 + t] = s * 0.2f;
        }
    }
}

// ---------------------------------------------------------------------------
// Pack weights (fp32 -> fp16) into MFMA B-fragment order.
// Frag (nt, ks), lane l, elem j holds W[ks*32 + (l>>4)*8 + j][nt*16 + (l&15)].
// Stored contiguously: P[((nt*KST + ks)*64 + l)*8 + j] -> one half8 per lane.
// Grid: 128 (mW2) + 112 (mW3) + 112 (oW1 rows 0..223) + 128 (oW2) = 480 blocks x 64.
// ---------------------------------------------------------------------------
__global__ void pack_weights(const float* __restrict__ mW2, const float* __restrict__ mW3,
                             const float* __restrict__ oW1, const float* __restrict__ oW2,
                             _Float16* __restrict__ PB2, _Float16* __restrict__ PB3,
                             _Float16* __restrict__ PO1, _Float16* __restrict__ PO2)
{
    int blk = blockIdx.x;
    int l = threadIdx.x;
    const float* W; _Float16* P; int LD;
    if (blk < 128)      { W = mW2; P = PB2; LD = 256; }
    else if (blk < 240) { blk -= 128; W = mW3; P = PB3; LD = 224; }
    else if (blk < 352) { blk -= 240; W = oW1; P = PO1; LD = 256; }
    else                { blk -= 352; W = oW2; P = PO2; LD = 256; }
    int KST = (P == PO1) ? 7 : 8;
    int nt = blk / KST, ks = blk - nt * KST;
    int n  = nt * 16 + (l & 15);
    int k0 = ks * 32 + (l >> 4) * 8;
    half8 v;
    #pragma unroll
    for (int j = 0; j < 8; ++j) v[j] = (_Float16)W[(size_t)(k0 + j) * LD + n];
    *(half8*)&P[(size_t)(blk * 64 + l) * 8] = v;
}

// ---------------------------------------------------------------------------
// One GEMM phase on the matrix pipe.
// Wave computes 4 m-tiles (all 64 rows) x NTW n-tiles, K = KST*32.
// A from swizzled LDS (ds_read_b128), B from packed global frags (L2).
// ---------------------------------------------------------------------------
template<int NTW, int KST>
static __device__ __forceinline__ void mma_phase(const half8* __restrict__ Wp,
                                                 const char* actp, int lane,
                                                 f4 acc[4][4])
{
    #pragma unroll
    for (int mt = 0; mt < 4; ++mt)
        #pragma unroll
        for (int nt = 0; nt < NTW; ++nt)
            acc[mt][nt] = (f4){0.f, 0.f, 0.f, 0.f};

    for (int ks = 0; ks < KST; ++ks) {
        int kb = ks * 64 + ((lane >> 4) << 4);   // (ks*32 + (lane>>4)*8) * 2 bytes
        half8 a[4];
        #pragma unroll
        for (int mt = 0; mt < 4; ++mt) {
            int row = mt * 16 + (lane & 15);
            a[mt] = *(const half8*)(actp + ((row * 512 + kb) ^ ((row & 7) << 4)));
        }
        #pragma unroll
        for (int nt = 0; nt < NTW; ++nt) {
            half8 b = Wp[(nt * KST + ks) * 64 + lane];
            #pragma unroll
            for (int mt = 0; mt < 4; ++mt)
                acc[mt][nt] = __builtin_amdgcn_mfma_f32_16x16x32_f16(a[mt], b, acc[mt][nt], 0, 0, 0);
        }
    }
}

// ---------------------------------------------------------------------------
// Fused kernel: 64 pairs / block, 256 threads (4 waves).
// Wave wc owns output columns [wc*64, wc*64+64), all 64 rows.
// ---------------------------------------------------------------------------
__global__ __launch_bounds__(256, 2)
void fused_mfma(const float* __restrict__ h_abs,
                const float* __restrict__ mb2, const float* __restrict__ mb3,
                const float* __restrict__ ob2,
                const float* __restrict__ oW3, const float* __restrict__ ob3,
                const float* __restrict__ E1, const float* __restrict__ F1,
                const float* __restrict__ Fo, const float* __restrict__ S,
                const half8* __restrict__ PB2, const half8* __restrict__ PB3,
                const half8* __restrict__ PO1, const half8* __restrict__ PO2,
                float* __restrict__ out)
{
    __shared__ char act[MBLK * 512];   // 32 KB f16 activations [64][256]

    const int t    = threadIdx.x;
    const int lane = t & 63;
    const int wc   = t >> 6;
    const int p0   = blockIdx.x * MBLK;
    const int lr   = lane & 15;
    const int lq   = lane >> 4;

    // ---- Phase A: h1 = silu(E1[e] + F1[b])  -> act (f16) ----
    {
        #pragma unroll
        for (int i = 0; i < 8; ++i) {
            int c   = i * 256 + t;        // 0..2047 chunk id
            int row = c >> 5;
            int c0  = (c & 31) * 8;
            int p = p0 + row;
            int b = p / NE;
            int e = p - b * NE;
            const float4* ep = (const float4*)&E1[e * HID + c0];
            const float4* fp = (const float4*)&F1[b * HID + c0];
            float4 e0 = ep[0], e1 = ep[1];
            float4 f0 = fp[0], f1 = fp[1];
            half8 hv;
            hv[0] = (_Float16)silu_f(e0.x + f0.x);
            hv[1] = (_Float16)silu_f(e0.y + f0.y);
            hv[2] = (_Float16)silu_f(e0.z + f0.z);
            hv[3] = (_Float16)silu_f(e0.w + f0.w);
            hv[4] = (_Float16)silu_f(e1.x + f1.x);
            hv[5] = (_Float16)silu_f(e1.y + f1.y);
            hv[6] = (_Float16)silu_f(e1.z + f1.z);
            hv[7] = (_Float16)silu_f(e1.w + f1.w);
            *(half8*)(act + swz(row, c0 * 2)) = hv;
        }
    }
    __syncthreads();

    f4 acc[4][4];

    // ---- Phase B: h2 = silu(h1 @ mW2 + mb2) ----
    mma_phase<4, 8>(PB2 + (wc * 4) * 8 * 64, act, lane, acc);
    __syncthreads();
    #pragma unroll
    for (int nt = 0; nt < 4; ++nt) {
        int n = wc * 64 + nt * 16 + lr;
        float bias = mb2[n];
        #pragma unroll
        for (int mt = 0; mt < 4; ++mt)
            #pragma unroll
            for (int r = 0; r < 4; ++r) {
                int row = mt * 16 + lq * 4 + r;
                *(_Float16*)(act + swz(row, n * 2)) =
                    (_Float16)silu_f(acc[mt][nt][r] + bias);
            }
    }
    __syncthreads();

    // ---- Phase C: g = h2 @ mW3 + mb3 ; fused invariant transform ----
    if (wc < 3) mma_phase<4, 8>(PB3 + (wc * 4) * 8 * 64, act, lane, acc);
    else        mma_phase<2, 8>(PB3 + 12 * 8 * 64,       act, lane, acc);
    __syncthreads();
    #pragma unroll
    for (int nt = 0; nt < 4; ++nt) {
        int n = wc * 64 + nt * 16 + lr;
        if (n < NCOP) {
            float bias = mb3[n];
            #pragma unroll
            for (int mt = 0; mt < 4; ++mt)
                #pragma unroll
                for (int r = 0; r < 4; ++r) {
                    int row = mt * 16 + lq * 4 + r;
                    int p = p0 + row;
                    int b = p / NE;
                    float g = acc[mt][nt][r] + bias;
                    float invv;
                    if (n < 128) invv = h_abs[b * DIN + n] * g;       // l=0 scalars
                    else         invv = sqrtf(g * g * S[b * 96 + (n - 128)] + 1e-8f);
                    *(_Float16*)(act + swz(row, n * 2)) = (_Float16)invv;
                }
        }
    }
    __syncthreads();

    // ---- Phase D: o1 = silu(inv @ oW1[0:224] + Fo[b])  (Fo includes ob1) ----
    mma_phase<4, 7>(PO1 + (wc * 4) * 7 * 64, act, lane, acc);
    __syncthreads();
    #pragma unroll
    for (int nt = 0; nt < 4; ++nt) {
        int n = wc * 64 + nt * 16 + lr;
        #pragma unroll
        for (int mt = 0; mt < 4; ++mt)
            #pragma unroll
            for (int r = 0; r < 4; ++r) {
                int row = mt * 16 + lq * 4 + r;
                int p = p0 + row;
                int b = p / NE;
                *(_Float16*)(act + swz(row, n * 2)) =
                    (_Float16)silu_f(acc[mt][nt][r] + Fo[b * HID + n]);
            }
    }
    __syncthreads();

    // ---- Phase E: o2 = silu(o1 @ oW2 + ob2) ----
    mma_phase<4, 8>(PO2 + (wc * 4) * 8 * 64, act, lane, acc);
    __syncthreads();
    #pragma unroll
    for (int nt = 0; nt < 4; ++nt) {
        int n = wc * 64 + nt * 16 + lr;
        float bias = ob2[n];
        #pragma unroll
        for (int mt = 0; mt < 4; ++mt)
            #pragma unroll
            for (int r = 0; r < 4; ++r) {
                int row = mt * 16 + lq * 4 + r;
                *(_Float16*)(act + swz(row, n * 2)) =
                    (_Float16)silu_f(acc[mt][nt][r] + bias);
            }
    }
    __syncthreads();

    // ---- Phase F: out[p] = o2[p] . oW3 + ob3  (fp32 dot, 4 threads/pair) ----
    {
        int pF  = t >> 2;   // 0..63
        int seg = t & 3;    // 0..3, each covers 64 f16 = 8 chunks
        float s = 0.f;
        #pragma unroll
        for (int q = 0; q < 8; ++q) {
            half8 v = *(const half8*)(act + swz(pF, seg * 128 + q * 16));
            const float4* wp = (const float4*)&oW3[seg * 64 + q * 8];
            float4 wa = wp[0], wb = wp[1];
            s += (float)v[0] * wa.x + (float)v[1] * wa.y +
                 (float)v[2] * wa.z + (float)v[3] * wa.w +
                 (float)v[4] * wb.x + (float)v[5] * wb.y +
                 (float)v[6] * wb.z + (float)v[7] * wb.w;
        }
        s += __shfl_xor(s, 1, 64);
        s += __shfl_xor(s, 2, 64);
        if (seg == 0) out[p0 + pF] = s + ob3[0];
    }
}

extern "C" void kernel_launch(void* const* d_in, const int* in_sizes, int n_in,
                              void* d_out, int out_size, void* d_ws, size_t ws_size,
                              hipStream_t stream) {
    const float* h_abs  = (const float*)d_in[0];
    const float* e_feat = (const float*)d_in[1];
    const float* field  = (const float*)d_in[2];
    const float* mW1 = (const float*)d_in[3];
    const float* mb1 = (const float*)d_in[4];
    const float* mW2 = (const float*)d_in[5];
    const float* mb2 = (const float*)d_in[6];
    const float* mW3 = (const float*)d_in[7];
    const float* mb3 = (const float*)d_in[8];
    const float* oW1 = (const float*)d_in[9];
    const float* ob1 = (const float*)d_in[10];
    const float* oW2 = (const float*)d_in[11];
    const float* ob2 = (const float*)d_in[12];
    const float* oW3 = (const float*)d_in[13];
    const float* ob3 = (const float*)d_in[14];
    float* out = (float*)d_out;

    // Workspace layout
    float* ws = (float*)d_ws;
    float* E1 = ws;                      // 400*256 = 102400 f
    float* F1 = E1 + NE * HID;           // 65536 f
    float* Fo = F1 + BB * HID;           // 65536 f
    float* S  = Fo + BB * HID;           // 24576 f
    _Float16* PB2 = (_Float16*)(S + BB * 96);   // 16*8*64*8 = 65536 h
    _Float16* PB3 = PB2 + 16 * 8 * 64 * 8;      // 14*8*64*8 = 57344 h
    _Float16* PO1 = PB3 + 14 * 8 * 64 * 8;      // 16*7*64*8 = 57344 h
    _Float16* PO2 = PO1 + 16 * 7 * 64 * 8;      // 16*8*64*8 = 65536 h

    precompute_kernel<<<NE + 3 * BB, 256, 0, stream>>>(
        h_abs, e_feat, field, mW1, mb1, oW1, ob1, E1, F1, Fo, S);

    pack_weights<<<480, 64, 0, stream>>>(
        mW2, mW3, oW1, oW2, PB2, PB3, PO1, PO2);

    fused_mfma<<<NBLK, 256, 0, stream>>>(
        h_abs, mb2, mb3, ob2, oW3, ob3,
        E1, F1, Fo, S,
        (const half8*)PB2, (const half8*)PB3, (const half8*)PO1, (const half8*)PO2,
        out);
}